// Round 6
// baseline (725.801 us; speedup 1.0000x reference)
//
#include <hip/hip_runtime.h>

#define Bn 8
#define Cc 64
#define CO 64
#define Hh 128
#define Ww 128
#define Kk 9
#define HW (Hh*Ww)

typedef __attribute__((ext_vector_type(8))) short bf16x8;
typedef __attribute__((ext_vector_type(4))) float f32x4;

__device__ __forceinline__ short f2bf(float f) {
    unsigned u = __float_as_uint(f);
    u = (u + 0x7FFFu + ((u >> 16) & 1u)) >> 16;   // RNE
    return (short)u;
}

// XCD-aware swizzle: 2048 blocks, 8 XCDs, 256-block chunks (bijective: 2048%8==0)
__device__ __forceinline__ int xcd_swizzle(int bid) {
    return ((bid & 7) << 8) | (bid >> 3);
}

// ---------------- kernel 1: input NCHW fp32 -> NHWC bf16 ----------------
__global__ __launch_bounds__(256) void transpose_in_kernel(
    const float* __restrict__ in, short* __restrict__ in_t)
{
    __shared__ float tile[64 * 65];
    int bid  = xcd_swizzle(blockIdx.x);   // match main kernel's XCD mapping
    int xblk = bid & 1;
    int row  = bid >> 1;            // b*H + y
    int y    = row & (Hh - 1);
    int b    = row >> 7;
    int x0   = xblk << 6;
    int t    = threadIdx.x;

    int x  = t & 63;
    int cq = t >> 6;
    const float* src = in + (size_t)b * Cc * HW + (size_t)y * Ww + x0;
#pragma unroll
    for (int i = 0; i < 16; ++i) {
        int c = cq * 16 + i;
        tile[c * 65 + x] = src[(size_t)c * HW + x];
    }
    __syncthreads();
    int c2 = t & 63;
    int xq = t >> 6;
    short* dst = in_t + ((size_t)(b * Hh + y) * Ww + x0) * Cc;
#pragma unroll
    for (int i = 0; i < 16; ++i) {
        int xx = xq * 16 + i;
        dst[(size_t)xx * Cc + c2] = f2bf(tile[c2 * 65 + xx]);
    }
}

// ---------------- kernel 2: weight fp32 [co][c][k] -> bf16 [k][co][c] ----------------
__global__ __launch_bounds__(256) void prep_w_kernel(
    const float* __restrict__ w, short* __restrict__ w_t)
{
    int idx = blockIdx.x * 256 + threadIdx.x;
    if (idx < Kk * CO * Cc) {
        int k  = idx >> 12;
        int co = (idx >> 6) & 63;
        int c  = idx & 63;
        w_t[idx] = f2bf(w[((size_t)co * Cc + c) * Kk + k]);
    }
}

// ---------------- kernel 3: fused sample + corner-GEMM MFMA ----------------
// Gathered bf16 corner rows feed MFMA B-operand RAW (no unpack/blend/pack VALU).
// Bilinear blend moves into f32 D-space: acc[f] += cw[corner] * (W x X_corner).
// Lane map == MFMA B-fragment map: px = 16*wv + (l&15), channel group g = l>>4.
__global__ __launch_bounds__(256, 4) void dcn_main_kernel(
    const short* __restrict__ in_t,   // [B][H][W][C] bf16
    const float* __restrict__ offm,   // [B][27][H][W] fp32
    const short* __restrict__ w_t,    // [K][CO][C] bf16
    const float* __restrict__ bias,   // [CO] fp32
    float* __restrict__ out)          // [B][CO][H][W] fp32
{
    __shared__ short s_W[2][64][72];  // weight bf16 [co][c], pad 72

    int bid  = xcd_swizzle(blockIdx.x);
    int xblk = bid & 1;
    int row  = bid >> 1;
    int y    = row & (Hh - 1);
    int b    = row >> 7;
    int x0   = xblk << 6;
    int t    = threadIdx.x;
    int l    = t & 63;
    int wv   = t >> 6;                // wave 0..3
    int lm   = l & 15;                // px within stripe == MFMA col
    int g    = l >> 4;                // channel group == MFMA k-chunk
    int px   = (wv << 4) + lm;

    const float* offb = offm + (size_t)b * 27 * HW + (size_t)y * Ww + x0 + px;
    const short* inb  = in_t + (size_t)b * HW * Cc;

    // W staging indices (256 threads cover 64co x 64c)
    int wco = t >> 2;
    int wc0 = (t & 3) << 4;

    f32x4 acc[4] = {{0.f,0.f,0.f,0.f},{0.f,0.f,0.f,0.f},{0.f,0.f,0.f,0.f},{0.f,0.f,0.f,0.f}};

    bf16x8 r[4][2];   // raw corner gathers [corner][half] — feed MFMA directly
    float  cw[4];     // corner weights (validity + mask folded)
    uint4  wq[2];     // in-flight W slice

    auto w_load = [&](int k) {
        const uint4* wk = (const uint4*)(w_t + (size_t)k * (CO * Cc) + 16 * t);
        wq[0] = wk[0];
        wq[1] = wk[1];
    };
    auto w_store = [&](int nb) {
        *(uint4*)&s_W[nb][wco][wc0]     = wq[0];
        *(uint4*)&s_W[nb][wco][wc0 + 8] = wq[1];
    };

    auto stage_gather = [&](int k) {
        // per-pixel offsets reloaded each k (coalesced, L1-shared across waves)
        float dy = offb[(size_t)(2 * k) * HW];
        float dx = offb[(size_t)(2 * k + 1) * HW];
        float ml = offb[(size_t)(18 + k) * HW];
        float m  = __builtin_amdgcn_rcpf(1.0f + __expf(-ml));

        float ys = (float)(y + (k / 3) - 1) + dy;
        float xs = (float)(x0 + px + (k % 3) - 1) + dx;
        float yf = floorf(ys), xf = floorf(xs);
        int y0i = (int)yf, x0i = (int)xf;
        float wy = ys - yf, wx = xs - xf;

        bool vy0 = (unsigned)y0i < (unsigned)Hh;
        bool vy1 = (unsigned)(y0i + 1) < (unsigned)Hh;
        bool vx0 = (unsigned)x0i < (unsigned)Ww;
        bool vx1 = (unsigned)(x0i + 1) < (unsigned)Ww;

        int cy0 = min(max(y0i, 0), Hh - 1);
        int cy1 = min(max(y0i + 1, 0), Hh - 1);
        int cx0 = min(max(x0i, 0), Ww - 1);
        int cx1 = min(max(x0i + 1, 0), Ww - 1);

        cw[0] = (vy0 && vx0) ? (1.0f - wy) * (1.0f - wx) * m : 0.0f;
        cw[1] = (vy0 && vx1) ? (1.0f - wy) * wx * m : 0.0f;
        cw[2] = (vy1 && vx0) ? wy * (1.0f - wx) * m : 0.0f;
        cw[3] = (vy1 && vx1) ? wy * wx * m : 0.0f;

        int idx[4] = {cy0 * Ww + cx0, cy0 * Ww + cx1, cy1 * Ww + cx0, cy1 * Ww + cx1};
#pragma unroll
        for (int cc = 0; cc < 4; ++cc) {
            // lanes {px, px+16, px+32, px+48} (g=0..3) cover one 64B half-row
            const short* p = inb + (size_t)idx[cc] * Cc + (g << 3);
            r[cc][0] = *(const bf16x8*)p;          // channels 8g   .. 8g+7
            r[cc][1] = *(const bf16x8*)(p + 32);   // channels 32+8g.. +7
        }
    };

    // prologue
    w_load(0);
    stage_gather(0);
    w_store(0);        // vmcnt(8): W loads (oldest) drained, gathers stay in flight
    __syncthreads();

#pragma unroll
    for (int k = 0; k < Kk; ++k) {
        int cb = k & 1;

        // hoist A fragments for this k (8 ds_read_b128)
        bf16x8 A0[4], A1[4];
#pragma unroll
        for (int f = 0; f < 4; ++f) {
            A0[f] = *(const bf16x8*)&s_W[cb][(f << 4) + lm][(g << 3)];
            A1[f] = *(const bf16x8*)&s_W[cb][(f << 4) + lm][32 + (g << 3)];
        }

        if (k < Kk - 1) w_load(k + 1);   // issue next W loads early

        // corner GEMMs: tmp = W x X_corner (f32), then acc += cw[corner]*tmp
#pragma unroll
        for (int cc = 0; cc < 4; ++cc) {
            float w = cw[cc];
#pragma unroll
            for (int f = 0; f < 4; ++f) {
                f32x4 tmp = __builtin_amdgcn_mfma_f32_16x16x32_bf16(
                    A0[f], r[cc][0], (f32x4){0.f,0.f,0.f,0.f}, 0, 0, 0);
                tmp = __builtin_amdgcn_mfma_f32_16x16x32_bf16(
                    A1[f], r[cc][1], tmp, 0, 0, 0);
#pragma unroll
                for (int j = 0; j < 4; ++j)
                    acc[f][j] = fmaf(w, tmp[j], acc[f][j]);
            }
        }

        if (k < Kk - 1) {
            stage_gather(k + 1);   // overwrites r AFTER all MFMAs of k consumed it
            w_store(cb ^ 1);       // vmcnt(8): only W loads drained
            __syncthreads();
        }
    }

    // epilogue: lane l holds D[co = 16f + 4g + rr][px = 16wv + lm]
    float* outb = out + (size_t)b * CO * HW + (size_t)y * Ww + x0 + (wv << 4) + lm;
#pragma unroll
    for (int f = 0; f < 4; ++f) {
#pragma unroll
        for (int rr = 0; rr < 4; ++rr) {
            int co = (f << 4) + (g << 2) + rr;
            outb[(size_t)co * HW] = acc[f][rr] + bias[co];
        }
    }
}

// ---------------- launcher ----------------
extern "C" void kernel_launch(void* const* d_in, const int* in_sizes, int n_in,
                              void* d_out, int out_size, void* d_ws, size_t ws_size,
                              hipStream_t stream)
{
    const float* in   = (const float*)d_in[0];
    const float* offm = (const float*)d_in[1];
    const float* w    = (const float*)d_in[2];
    const float* bias = (const float*)d_in[3];
    float* out = (float*)d_out;

    short* in_t = (short*)d_ws;                          // 8*128*128*64 bf16 = 16 MiB
    short* w_t  = in_t + (size_t)Bn * HW * Cc;           // 9*64*64 bf16 = 72 KiB

    transpose_in_kernel<<<Bn * Hh * 2, 256, 0, stream>>>(in, in_t);
    prep_w_kernel<<<(Kk * CO * Cc + 255) / 256, 256, 0, stream>>>(w, w_t);
    dcn_main_kernel<<<Bn * Hh * 2, 256, 0, stream>>>(in_t, offm, w_t, bias, out);
}

// Round 7
// 673.205 us; speedup vs baseline: 1.0781x; 1.0781x over previous
//
#include <hip/hip_runtime.h>

#define Bn 8
#define Cc 64
#define CO 64
#define Hh 128
#define Ww 128
#define Kk 9
#define HW (Hh*Ww)

typedef __attribute__((ext_vector_type(8))) short bf16x8;
typedef __attribute__((ext_vector_type(4))) float f32x4;

__device__ __forceinline__ short f2bf(float f) {
    unsigned u = __float_as_uint(f);
    u = (u + 0x7FFFu + ((u >> 16) & 1u)) >> 16;   // RNE
    return (short)u;
}

// XCD-aware swizzle: 2048 blocks, 8 XCDs, 256-block chunks (bijective: 2048%8==0)
__device__ __forceinline__ int xcd_swizzle(int bid) {
    return ((bid & 7) << 8) | (bid >> 3);
}

// ---------------- kernel 1: input NCHW fp32 -> NHWC bf16 ----------------
__global__ __launch_bounds__(256) void transpose_in_kernel(
    const float* __restrict__ in, short* __restrict__ in_t)
{
    __shared__ float tile[64 * 65];
    int bid  = xcd_swizzle(blockIdx.x);   // match main kernel's XCD mapping
    int xblk = bid & 1;
    int row  = bid >> 1;            // b*H + y
    int y    = row & (Hh - 1);
    int b    = row >> 7;
    int x0   = xblk << 6;
    int t    = threadIdx.x;

    int x  = t & 63;
    int cq = t >> 6;
    const float* src = in + (size_t)b * Cc * HW + (size_t)y * Ww + x0;
#pragma unroll
    for (int i = 0; i < 16; ++i) {
        int c = cq * 16 + i;
        tile[c * 65 + x] = src[(size_t)c * HW + x];
    }
    __syncthreads();
    int c2 = t & 63;
    int xq = t >> 6;
    short* dst = in_t + ((size_t)(b * Hh + y) * Ww + x0) * Cc;
#pragma unroll
    for (int i = 0; i < 16; ++i) {
        int xx = xq * 16 + i;
        dst[(size_t)xx * Cc + c2] = f2bf(tile[c2 * 65 + xx]);
    }
}

// ---------------- kernel 2: weight fp32 [co][c][k] -> bf16 [k][co][c] ----------------
__global__ __launch_bounds__(256) void prep_w_kernel(
    const float* __restrict__ w, short* __restrict__ w_t)
{
    int idx = blockIdx.x * 256 + threadIdx.x;
    if (idx < Kk * CO * Cc) {
        int k  = idx >> 12;
        int co = (idx >> 6) & 63;
        int c  = idx & 63;
        w_t[idx] = f2bf(w[((size_t)co * Cc + c) * Kk + k]);
    }
}

// ---------------- kernel 3: fused sample + corner-GEMM MFMA ----------------
// Raw bf16 corner gathers feed MFMA B-operand directly; bilinear blend happens
// in f32 D-space (acc[f] += cw[corner] * (W x X_corner)).
// Register budget: __launch_bounds__(256,3) -> ~168 VGPR cap, 3 blocks/CU.
// r/cw explicitly double-buffered; A fragments loaded one pair at a time.
__global__ __launch_bounds__(256, 3) void dcn_main_kernel(
    const short* __restrict__ in_t,   // [B][H][W][C] bf16
    const float* __restrict__ offm,   // [B][27][H][W] fp32
    const short* __restrict__ w_t,    // [K][CO][C] bf16
    const float* __restrict__ bias,   // [CO] fp32
    float* __restrict__ out)          // [B][CO][H][W] fp32
{
    __shared__ short s_W[2][64][72];  // weight bf16 [co][c], pad 72 (2-way max)

    int bid  = xcd_swizzle(blockIdx.x);
    int xblk = bid & 1;
    int row  = bid >> 1;
    int y    = row & (Hh - 1);
    int b    = row >> 7;
    int x0   = xblk << 6;
    int t    = threadIdx.x;
    int l    = t & 63;
    int wv   = t >> 6;                // wave 0..3
    int lm   = l & 15;                // px within stripe == MFMA col
    int g    = l >> 4;                // channel group == MFMA k-chunk
    int px   = (wv << 4) + lm;

    const float* offb = offm + (size_t)b * 27 * HW + (size_t)y * Ww + x0 + px;
    const short* inb  = in_t + (size_t)b * HW * Cc;

    // W staging indices (256 threads cover 64co x 64c)
    int wco = t >> 2;
    int wc0 = (t & 3) << 4;

    f32x4 acc[4] = {{0.f,0.f,0.f,0.f},{0.f,0.f,0.f,0.f},{0.f,0.f,0.f,0.f},{0.f,0.f,0.f,0.f}};

    bf16x8 r[2][4][2];   // DOUBLE-buffered raw corner gathers [buf][corner][half]
    float  cw[2][4];     // double-buffered corner weights (validity+mask folded)
    uint4  wq[2];        // in-flight W slice

    auto w_load = [&](int k) {
        const uint4* wk = (const uint4*)(w_t + (size_t)k * (CO * Cc) + 16 * t);
        wq[0] = wk[0];
        wq[1] = wk[1];
    };
    auto w_store = [&](int nb) {
        *(uint4*)&s_W[nb][wco][wc0]     = wq[0];
        *(uint4*)&s_W[nb][wco][wc0 + 8] = wq[1];
    };

    auto stage_gather = [&](int k, int nb) {
        // per-pixel offsets reloaded each k (coalesced, L1-hot across waves)
        float dy = offb[(size_t)(2 * k) * HW];
        float dx = offb[(size_t)(2 * k + 1) * HW];
        float ml = offb[(size_t)(18 + k) * HW];
        float m  = __builtin_amdgcn_rcpf(1.0f + __expf(-ml));

        float ys = (float)(y + (k / 3) - 1) + dy;
        float xs = (float)(x0 + px + (k % 3) - 1) + dx;
        float yf = floorf(ys), xf = floorf(xs);
        int y0i = (int)yf, x0i = (int)xf;
        float wy = ys - yf, wx = xs - xf;

        bool vy0 = (unsigned)y0i < (unsigned)Hh;
        bool vy1 = (unsigned)(y0i + 1) < (unsigned)Hh;
        bool vx0 = (unsigned)x0i < (unsigned)Ww;
        bool vx1 = (unsigned)(x0i + 1) < (unsigned)Ww;

        int cy0 = min(max(y0i, 0), Hh - 1);
        int cy1 = min(max(y0i + 1, 0), Hh - 1);
        int cx0 = min(max(x0i, 0), Ww - 1);
        int cx1 = min(max(x0i + 1, 0), Ww - 1);

        cw[nb][0] = (vy0 && vx0) ? (1.0f - wy) * (1.0f - wx) * m : 0.0f;
        cw[nb][1] = (vy0 && vx1) ? (1.0f - wy) * wx * m : 0.0f;
        cw[nb][2] = (vy1 && vx0) ? wy * (1.0f - wx) * m : 0.0f;
        cw[nb][3] = (vy1 && vx1) ? wy * wx * m : 0.0f;

        int idx[4] = {cy0 * Ww + cx0, cy0 * Ww + cx1, cy1 * Ww + cx0, cy1 * Ww + cx1};
#pragma unroll
        for (int cc = 0; cc < 4; ++cc) {
            // lanes {px, px+16, px+32, px+48} (g=0..3) cover one 64B half-row
            const short* p = inb + (size_t)idx[cc] * Cc + (g << 3);
            r[nb][cc][0] = *(const bf16x8*)p;          // channels 8g   .. 8g+7
            r[nb][cc][1] = *(const bf16x8*)(p + 32);   // channels 32+8g.. +7
        }
    };

    // prologue
    w_load(0);
    stage_gather(0, 0);
    w_store(0);
    __syncthreads();

#pragma unroll
    for (int k = 0; k < Kk; ++k) {
        int cb = k & 1;

        if (k < Kk - 1) {
            w_load(k + 1);              // issue W loads, then gathers -> buf cb^1
            stage_gather(k + 1, cb ^ 1);
        }

        // corner GEMMs: tmp = W x X_corner (f32), acc += cw[corner]*tmp.
        // f-outer: one A pair (8 VGPR) live at a time, reused for 4 corners.
#pragma unroll
        for (int f = 0; f < 4; ++f) {
            bf16x8 A0 = *(const bf16x8*)&s_W[cb][(f << 4) + lm][(g << 3)];
            bf16x8 A1 = *(const bf16x8*)&s_W[cb][(f << 4) + lm][32 + (g << 3)];
#pragma unroll
            for (int cc = 0; cc < 4; ++cc) {
                f32x4 tmp = __builtin_amdgcn_mfma_f32_16x16x32_bf16(
                    A0, r[cb][cc][0], (f32x4){0.f,0.f,0.f,0.f}, 0, 0, 0);
                tmp = __builtin_amdgcn_mfma_f32_16x16x32_bf16(
                    A1, r[cb][cc][1], tmp, 0, 0, 0);
                float w = cw[cb][cc];
#pragma unroll
                for (int j = 0; j < 4; ++j)
                    acc[f][j] = fmaf(w, tmp[j], acc[f][j]);
            }
        }

        if (k < Kk - 1) {
            w_store(cb ^ 1);   // vmcnt(8): W drained, gathers stay in flight
            __syncthreads();
        }
    }

    // epilogue: lane l holds D[co = 16f + 4g + rr][px = 16wv + lm]
    float* outb = out + (size_t)b * CO * HW + (size_t)y * Ww + x0 + (wv << 4) + lm;
#pragma unroll
    for (int f = 0; f < 4; ++f) {
#pragma unroll
        for (int rr = 0; rr < 4; ++rr) {
            int co = (f << 4) + (g << 2) + rr;
            outb[(size_t)co * HW] = acc[f][rr] + bias[co];
        }
    }
}

// ---------------- launcher ----------------
extern "C" void kernel_launch(void* const* d_in, const int* in_sizes, int n_in,
                              void* d_out, int out_size, void* d_ws, size_t ws_size,
                              hipStream_t stream)
{
    const float* in   = (const float*)d_in[0];
    const float* offm = (const float*)d_in[1];
    const float* w    = (const float*)d_in[2];
    const float* bias = (const float*)d_in[3];
    float* out = (float*)d_out;

    short* in_t = (short*)d_ws;                          // 8*128*128*64 bf16 = 16 MiB
    short* w_t  = in_t + (size_t)Bn * HW * Cc;           // 9*64*64 bf16 = 72 KiB

    transpose_in_kernel<<<Bn * Hh * 2, 256, 0, stream>>>(in, in_t);
    prep_w_kernel<<<(Kk * CO * Cc + 255) / 256, 256, 0, stream>>>(w, w_t);
    dcn_main_kernel<<<Bn * Hh * 2, 256, 0, stream>>>(in_t, offm, w_t, bias, out);
}

// Round 8
// 144.007 us; speedup vs baseline: 5.0400x; 4.6748x over previous
//
#include <hip/hip_runtime.h>

#define Bn 8
#define Cc 64
#define CO 64
#define Hh 128
#define Ww 128
#define Kk 9
#define HW (Hh*Ww)

typedef __attribute__((ext_vector_type(8))) short bf16x8;
typedef __attribute__((ext_vector_type(4))) float f32x4;

__device__ __forceinline__ short f2bf(float f) {
    unsigned u = __float_as_uint(f);
    u = (u + 0x7FFFu + ((u >> 16) & 1u)) >> 16;   // RNE
    return (short)u;
}

// XCD-aware swizzle: 2048 blocks, 8 XCDs, 256-block chunks (bijective: 2048%8==0)
__device__ __forceinline__ int xcd_swizzle(int bid) {
    return ((bid & 7) << 8) | (bid >> 3);
}

// ---------------- kernel 1: input NCHW fp32 -> NHWC bf16 ----------------
__global__ __launch_bounds__(256) void transpose_in_kernel(
    const float* __restrict__ in, short* __restrict__ in_t)
{
    __shared__ float tile[64 * 65];
    int bid  = xcd_swizzle(blockIdx.x);   // match main kernel's XCD mapping
    int xblk = bid & 1;
    int row  = bid >> 1;            // b*H + y
    int y    = row & (Hh - 1);
    int b    = row >> 7;
    int x0   = xblk << 6;
    int t    = threadIdx.x;

    int x  = t & 63;
    int cq = t >> 6;
    const float* src = in + (size_t)b * Cc * HW + (size_t)y * Ww + x0;
#pragma unroll
    for (int i = 0; i < 16; ++i) {
        int c = cq * 16 + i;
        tile[c * 65 + x] = src[(size_t)c * HW + x];
    }
    __syncthreads();
    int c2 = t & 63;
    int xq = t >> 6;
    short* dst = in_t + ((size_t)(b * Hh + y) * Ww + x0) * Cc;
#pragma unroll
    for (int i = 0; i < 16; ++i) {
        int xx = xq * 16 + i;
        dst[(size_t)xx * Cc + c2] = f2bf(tile[c2 * 65 + xx]);
    }
}

// ---------------- kernel 2: weight fp32 [co][c][k] -> bf16 [k][co][c] ----------------
__global__ __launch_bounds__(256) void prep_w_kernel(
    const float* __restrict__ w, short* __restrict__ w_t)
{
    int idx = blockIdx.x * 256 + threadIdx.x;
    if (idx < Kk * CO * Cc) {
        int k  = idx >> 12;
        int co = (idx >> 6) & 63;
        int c  = idx & 63;
        w_t[idx] = f2bf(w[((size_t)co * Cc + c) * Kk + k]);
    }
}

// ---------------- kernel 3: fused sample + corner-GEMM MFMA, no LDS ----------------
// Raw bf16 corner gathers feed MFMA B directly; bilinear blend in f32 D-space:
// acc += cw[corner] * (W x X_corner). W fragments read straight from global
// (72KB, L1/L2-hot) -> NO LDS, NO barriers in the k-loop.
// ALL per-thread state is named scalars/vectors (no arrays -> no rule-#20 scratch).
__global__ __launch_bounds__(256, 4) void dcn_main_kernel(
    const short* __restrict__ in_t,   // [B][H][W][C] bf16
    const float* __restrict__ offm,   // [B][27][H][W] fp32
    const short* __restrict__ w_t,    // [K][CO][C] bf16
    const float* __restrict__ bias,   // [CO] fp32
    float* __restrict__ out)          // [B][CO][H][W] fp32
{
    int bid  = xcd_swizzle(blockIdx.x);
    int xblk = bid & 1;
    int row  = bid >> 1;
    int y    = row & (Hh - 1);
    int b    = row >> 7;
    int x0   = xblk << 6;
    int t    = threadIdx.x;
    int l    = t & 63;
    int wv   = t >> 6;                // wave 0..3
    int lm   = l & 15;                // px within stripe == MFMA col
    int g    = l >> 4;                // channel group == MFMA k-chunk
    int px   = (wv << 4) + lm;

    const float* offb = offm + (size_t)b * 27 * HW + (size_t)y * Ww + x0 + px;
    const short* inb  = in_t + (size_t)b * HW * Cc;

    f32x4 accA = {0.f,0.f,0.f,0.f};
    f32x4 accB = {0.f,0.f,0.f,0.f};
    f32x4 accC = {0.f,0.f,0.f,0.f};
    f32x4 accD = {0.f,0.f,0.f,0.f};

    // named corner fragments + weights — NO arrays
    bf16x8 r0a, r0b, r1a, r1b, r2a, r2b, r3a, r3b;
    float  cw0, cw1, cw2, cw3;

    auto stage_gather = [&](int k) {
        float dy = offb[(size_t)(2 * k) * HW];
        float dx = offb[(size_t)(2 * k + 1) * HW];
        float ml = offb[(size_t)(18 + k) * HW];
        float m  = __builtin_amdgcn_rcpf(1.0f + __expf(-ml));

        float ys = (float)(y + (k / 3) - 1) + dy;
        float xs = (float)(x0 + px + (k % 3) - 1) + dx;
        float yf = floorf(ys), xf = floorf(xs);
        int y0i = (int)yf, x0i = (int)xf;
        float wy = ys - yf, wx = xs - xf;

        bool vy0 = (unsigned)y0i < (unsigned)Hh;
        bool vy1 = (unsigned)(y0i + 1) < (unsigned)Hh;
        bool vx0 = (unsigned)x0i < (unsigned)Ww;
        bool vx1 = (unsigned)(x0i + 1) < (unsigned)Ww;

        int cy0 = min(max(y0i, 0), Hh - 1);
        int cy1 = min(max(y0i + 1, 0), Hh - 1);
        int cx0 = min(max(x0i, 0), Ww - 1);
        int cx1 = min(max(x0i + 1, 0), Ww - 1);

        cw0 = (vy0 && vx0) ? (1.0f - wy) * (1.0f - wx) * m : 0.0f;
        cw1 = (vy0 && vx1) ? (1.0f - wy) * wx * m : 0.0f;
        cw2 = (vy1 && vx0) ? wy * (1.0f - wx) * m : 0.0f;
        cw3 = (vy1 && vx1) ? wy * wx * m : 0.0f;

        int i0 = cy0 * Ww + cx0;
        int i1 = cy0 * Ww + cx1;
        int i2 = cy1 * Ww + cx0;
        int i3 = cy1 * Ww + cx1;

        // lanes {px, px+16, px+32, px+48} (g=0..3) cover one 64B half-row each
        const short* p0 = inb + (size_t)i0 * Cc + (g << 3);
        const short* p1 = inb + (size_t)i1 * Cc + (g << 3);
        const short* p2 = inb + (size_t)i2 * Cc + (g << 3);
        const short* p3 = inb + (size_t)i3 * Cc + (g << 3);
        r0a = *(const bf16x8*)p0;        r0b = *(const bf16x8*)(p0 + 32);
        r1a = *(const bf16x8*)p1;        r1b = *(const bf16x8*)(p1 + 32);
        r2a = *(const bf16x8*)p2;        r2b = *(const bf16x8*)(p2 + 32);
        r3a = *(const bf16x8*)p3;        r3b = *(const bf16x8*)(p3 + 32);
    };

    stage_gather(0);

#define CORNER(A0, A1, RA, RB, CWT, ACC) do {                                   \
        f32x4 t_ = __builtin_amdgcn_mfma_f32_16x16x32_bf16(                     \
            (A0), (RA), (f32x4){0.f,0.f,0.f,0.f}, 0, 0, 0);                     \
        t_ = __builtin_amdgcn_mfma_f32_16x16x32_bf16((A1), (RB), t_, 0, 0, 0);  \
        (ACC)[0] = fmaf((CWT), t_[0], (ACC)[0]);                                \
        (ACC)[1] = fmaf((CWT), t_[1], (ACC)[1]);                                \
        (ACC)[2] = fmaf((CWT), t_[2], (ACC)[2]);                                \
        (ACC)[3] = fmaf((CWT), t_[3], (ACC)[3]);                                \
    } while (0)

#define DO_F(F, ACC) do {                                                       \
        bf16x8 A0_ = *(const bf16x8*)(wk + (F) * 1024);                         \
        bf16x8 A1_ = *(const bf16x8*)(wk + (F) * 1024 + 32);                    \
        CORNER(A0_, A1_, r0a, r0b, cw0, ACC);                                   \
        CORNER(A0_, A1_, r1a, r1b, cw1, ACC);                                   \
        CORNER(A0_, A1_, r2a, r2b, cw2, ACC);                                   \
        CORNER(A0_, A1_, r3a, r3b, cw3, ACC);                                   \
    } while (0)

    for (int k = 0; k < Kk; ++k) {
        // A fragments straight from global w_t[k] (coalesced, L1-hot)
        const short* wk = w_t + (size_t)k * (CO * Cc) + lm * 64 + (g << 3);
        DO_F(0, accA);
        DO_F(1, accB);
        DO_F(2, accC);
        DO_F(3, accD);
        if (k < Kk - 1) stage_gather(k + 1);   // r consumed; refill, no barrier
    }
#undef DO_F
#undef CORNER

    // epilogue: lane l holds D[co = 16F + 4g + rr][px = 16wv + lm]
    float* outb = out + (size_t)b * CO * HW + (size_t)y * Ww + x0 + (wv << 4) + lm;
#define WR_F(F, ACC) do {                                                       \
        _Pragma("unroll")                                                       \
        for (int rr = 0; rr < 4; ++rr) {                                        \
            int co = ((F) << 4) + (g << 2) + rr;                                \
            outb[(size_t)co * HW] = (ACC)[rr] + bias[co];                       \
        }                                                                       \
    } while (0)
    WR_F(0, accA);
    WR_F(1, accB);
    WR_F(2, accC);
    WR_F(3, accD);
#undef WR_F
}

// ---------------- launcher ----------------
extern "C" void kernel_launch(void* const* d_in, const int* in_sizes, int n_in,
                              void* d_out, int out_size, void* d_ws, size_t ws_size,
                              hipStream_t stream)
{
    const float* in   = (const float*)d_in[0];
    const float* offm = (const float*)d_in[1];
    const float* w    = (const float*)d_in[2];
    const float* bias = (const float*)d_in[3];
    float* out = (float*)d_out;

    short* in_t = (short*)d_ws;                          // 8*128*128*64 bf16 = 16 MiB
    short* w_t  = in_t + (size_t)Bn * HW * Cc;           // 9*64*64 bf16 = 72 KiB

    transpose_in_kernel<<<Bn * Hh * 2, 256, 0, stream>>>(in, in_t);
    prep_w_kernel<<<(Kk * CO * Cc + 255) / 256, 256, 0, stream>>>(w, w_t);
    dcn_main_kernel<<<Bn * Hh * 2, 256, 0, stream>>>(in_t, offm, w_t, bias, out);
}